// Round 4
// baseline (423.182 us; speedup 1.0000x reference)
//
#include <hip/hip_runtime.h>
#include <hip/hip_bf16.h>

typedef unsigned short u16;
typedef __attribute__((ext_vector_type(8))) __bf16 bf16x8;
typedef __attribute__((ext_vector_type(8))) u16 u16x8;
typedef __attribute__((ext_vector_type(4))) float f32x4;

__device__ __forceinline__ u16 f2bf(float f) {
    unsigned u = __float_as_uint(f);
    u += 0x7fffu + ((u >> 16) & 1u);   // round-to-nearest-even
    return (u16)(u >> 16);
}

__device__ __forceinline__ void gl_lds16(const void* g, void* l) {
    // direct global->LDS DMA, 16B/lane; LDS dest is wave-uniform base + lane*16
    __builtin_amdgcn_global_load_lds(
        (const __attribute__((address_space(1))) void*)g,
        (__attribute__((address_space(3))) void*)l, 16, 0, 0);
}

__device__ __forceinline__ bf16x8 cvt8(f32x4 lo, f32x4 hi) {
    u16x8 u;
    u[0] = f2bf(lo[0]); u[1] = f2bf(lo[1]); u[2] = f2bf(lo[2]); u[3] = f2bf(lo[3]);
    u[4] = f2bf(hi[0]); u[5] = f2bf(hi[1]); u[6] = f2bf(hi[2]); u[7] = f2bf(hi[3]);
    return __builtin_bit_cast(bf16x8, u);
}

// ---------- kernel 0: W1 [H=4][D=256][K=128] fp32 -> W1T [H][K][D] bf16 ----------
__global__ __launch_bounds__(256) void transpose_w1(const float* __restrict__ W1,
                                                    u16* __restrict__ W1T) {
    int idx = blockIdx.x * 256 + threadIdx.x;      // 131072 total
    int h = idx >> 15;
    int rem = idx & 32767;
    int k = rem >> 8;
    int d = rem & 255;
    float v = W1[((size_t)h * 256 + d) * 128 + k];
    W1T[idx] = f2bf(v);
}

// ---------- kernel 1: scores[N][4] = relu(x*W1+b1)*W2 + b2, m97-style MFMA ----------
// grid (n-tiles, heads). block 256 thr = 4 waves. BM=128 r (whole head), BN=128 n,
// BK=32, double-buffered LDS, all staging via global_load_lds(16).
// MFMA 16x16x32: C/D col=lane&15 (node), row=quad*4+reg (r). wave: 64r x 64n, 4x4 acc.
__global__ __launch_bounds__(256, 3) void score_kernel(
        const float* __restrict__ x, const u16* __restrict__ W1T,
        const float* __restrict__ b1, const float* __restrict__ W2,
        const float* __restrict__ b2, float* __restrict__ scores, int N) {
    __shared__ char sA[2][8192];    // [r 0..127][4 chunks of 16B, XOR-swizzled] bf16
    __shared__ char sB[2][16384];   // [n 0..127][8 chunks of 16B, XOR-swizzled] fp32
    __shared__ float red[2][128];

    const int t = threadIdx.x;
    const int wave = t >> 6;
    const int lane = t & 63;
    const int l15 = lane & 15;
    const int quad = lane >> 4;
    const int n0 = blockIdx.x * 128;
    const int h = blockIdx.y;
    const int valid = min(128, N - n0);

    const char* Abase = (const char*)(W1T + (size_t)h * 128 * 256);
    const char* Xbase = (const char*)x;

    f32x4 acc[4][4] = {};
    const int wr = (wave & 1) * 64;
    const int wn = (wave >> 1) * 64;

    // ---- staging: issue stage `it` into buffer `buf` ----
    auto stage = [&](int it, int buf) {
        const int k0 = it * 32;
        // A: 8KB = 512 slots of 16B; slot s = j*256 + t; r=s>>2, c=s&3
#pragma unroll
        for (int j = 0; j < 2; ++j) {
            int s = j * 256 + t;
            int r = s >> 2, c = s & 3;
            const char* g = Abase + (size_t)r * 512 + k0 * 2 + ((c ^ ((r >> 1) & 3)) * 16);
            gl_lds16(g, &sA[buf][j * 4096 + wave * 1024]);
        }
        // B: 16KB = 1024 slots; slot s = j*256 + t; n=s>>3, c=s&7 (fp32 rows 128B)
#pragma unroll
        for (int j = 0; j < 4; ++j) {
            int s = j * 256 + t;
            int n = s >> 3, c = s & 7;
            int nn = n0 + n; if (nn >= N) nn = N - 1;   // clamp, scores not stored
            const char* g = Xbase + (size_t)nn * 1024 + k0 * 4 + ((c ^ (n & 7)) * 16);
            gl_lds16(g, &sB[buf][j * 4096 + wave * 1024]);
        }
    };

    stage(0, 0);
    __syncthreads();

    for (int it = 0; it < 8; ++it) {
        if (it < 7) stage(it + 1, (it + 1) & 1);
        const int buf = it & 1;
        bf16x8 a[4], b[4];
#pragma unroll
        for (int rt = 0; rt < 4; ++rt) {
            int rl = wr + rt * 16 + l15;
            a[rt] = *reinterpret_cast<const bf16x8*>(
                &sA[buf][rl * 64 + ((quad ^ ((rl >> 1) & 3)) * 16)]);
        }
#pragma unroll
        for (int nt = 0; nt < 4; ++nt) {
            int nl = wn + nt * 16 + l15;
            f32x4 lo = *reinterpret_cast<const f32x4*>(
                &sB[buf][nl * 128 + (((2 * quad) ^ (nl & 7)) * 16)]);
            f32x4 hi = *reinterpret_cast<const f32x4*>(
                &sB[buf][nl * 128 + (((2 * quad + 1) ^ (nl & 7)) * 16)]);
            b[nt] = cvt8(lo, hi);
        }
#pragma unroll
        for (int rt = 0; rt < 4; ++rt)
#pragma unroll
            for (int nt = 0; nt < 4; ++nt)
                acc[rt][nt] = __builtin_amdgcn_mfma_f32_16x16x32_bf16(
                    a[rt], b[nt], acc[rt][nt], 0, 0, 0);
        __syncthreads();
    }

    // epilogue: part[nt] = sum_r relu(acc + b1) * W2   (r within lane+reg)
    float part[4] = {0.f, 0.f, 0.f, 0.f};
#pragma unroll
    for (int rt = 0; rt < 4; ++rt) {
        int rb = wr + rt * 16 + quad * 4;
        float4 w2v = *reinterpret_cast<const float4*>(W2 + h * 128 + rb);
        float4 b1v = *reinterpret_cast<const float4*>(b1 + h * 128 + rb);
#pragma unroll
        for (int nt = 0; nt < 4; ++nt) {
            f32x4 c = acc[rt][nt];
            part[nt] += fmaxf(c[0] + b1v.x, 0.f) * w2v.x
                      + fmaxf(c[1] + b1v.y, 0.f) * w2v.y
                      + fmaxf(c[2] + b1v.z, 0.f) * w2v.z
                      + fmaxf(c[3] + b1v.w, 0.f) * w2v.w;
        }
    }
#pragma unroll
    for (int nt = 0; nt < 4; ++nt) {
        float p = part[nt];
        p += __shfl_xor(p, 16, 64);
        p += __shfl_xor(p, 32, 64);
        if (lane < 16) red[wave & 1][wn + nt * 16 + l15] = p;
    }
    __syncthreads();
    if (t < valid)
        scores[(size_t)(n0 + t) * 4 + h] = red[0][t] + red[1][t] + b2[h];
}

// ---------- kernel 2: per-(graph,head) max and 1/sum(exp) ----------
__device__ __forceinline__ int lower_bound(const int* __restrict__ a, int n, int v) {
    int lo = 0, hi = n;
    while (lo < hi) {
        int mid = (lo + hi) >> 1;
        if (a[mid] < v) lo = mid + 1; else hi = mid;
    }
    return lo;
}

__global__ __launch_bounds__(256) void segstat_kernel(
        const float4* __restrict__ scores4, const int* __restrict__ seg,
        float4* __restrict__ mOut, float4* __restrict__ isOut, int N) {
    __shared__ float4 redm[4];
    __shared__ float4 reds[4];
    const int g = blockIdx.x;
    const int t = threadIdx.x;
    const int start = lower_bound(seg, N, g);
    const int end = lower_bound(seg, N, g + 1);

    float4 mx = make_float4(-3.4e38f, -3.4e38f, -3.4e38f, -3.4e38f);
    for (int i = start + t; i < end; i += 256) {
        float4 s = scores4[i];
        mx.x = fmaxf(mx.x, s.x); mx.y = fmaxf(mx.y, s.y);
        mx.z = fmaxf(mx.z, s.z); mx.w = fmaxf(mx.w, s.w);
    }
#pragma unroll
    for (int off = 1; off < 64; off <<= 1) {
        mx.x = fmaxf(mx.x, __shfl_xor(mx.x, off, 64));
        mx.y = fmaxf(mx.y, __shfl_xor(mx.y, off, 64));
        mx.z = fmaxf(mx.z, __shfl_xor(mx.z, off, 64));
        mx.w = fmaxf(mx.w, __shfl_xor(mx.w, off, 64));
    }
    if ((t & 63) == 0) redm[t >> 6] = mx;
    __syncthreads();
    mx = redm[0];
#pragma unroll
    for (int w = 1; w < 4; ++w) {
        mx.x = fmaxf(mx.x, redm[w].x); mx.y = fmaxf(mx.y, redm[w].y);
        mx.z = fmaxf(mx.z, redm[w].z); mx.w = fmaxf(mx.w, redm[w].w);
    }

    float4 sm = make_float4(0.f, 0.f, 0.f, 0.f);
    for (int i = start + t; i < end; i += 256) {
        float4 s = scores4[i];
        sm.x += expf(s.x - mx.x); sm.y += expf(s.y - mx.y);
        sm.z += expf(s.z - mx.z); sm.w += expf(s.w - mx.w);
    }
#pragma unroll
    for (int off = 1; off < 64; off <<= 1) {
        sm.x += __shfl_xor(sm.x, off, 64);
        sm.y += __shfl_xor(sm.y, off, 64);
        sm.z += __shfl_xor(sm.z, off, 64);
        sm.w += __shfl_xor(sm.w, off, 64);
    }
    if ((t & 63) == 0) reds[t >> 6] = sm;
    __syncthreads();
    if (t == 0) {
        float4 tot = reds[0];
        for (int w = 1; w < 4; ++w) {
            tot.x += reds[w].x; tot.y += reds[w].y;
            tot.z += reds[w].z; tot.w += reds[w].w;
        }
        bool nonempty = end > start;
        float4 m_out = nonempty ? mx : make_float4(0.f, 0.f, 0.f, 0.f);
        float4 is;
        is.x = (nonempty && tot.x > 0.f) ? 1.f / tot.x : 0.f;
        is.y = (nonempty && tot.y > 0.f) ? 1.f / tot.y : 0.f;
        is.z = (nonempty && tot.z > 0.f) ? 1.f / tot.z : 0.f;
        is.w = (nonempty && tot.w > 0.f) ? 1.f / tot.w : 0.f;
        mOut[g] = m_out;
        isOut[g] = is;
    }
}

// ---------- kernel 3: out[g][d] += avg_attn[n]*x[n][d]; 256-node strips, runs+atomics
__global__ __launch_bounds__(256) void wsum_kernel(
        const float* __restrict__ x, const float4* __restrict__ scores4,
        const int* __restrict__ seg, const float4* __restrict__ mArr,
        const float4* __restrict__ isArr, float* __restrict__ out, int N) {
    __shared__ float wl[256];
    __shared__ int gl[256];
    __shared__ unsigned long long bmask[4];
    const int t = threadIdx.x;
    const int n0 = blockIdx.x * 256;
    const int cnt = min(256, N - n0);

    int g = -1;
    float w = 0.f;
    if (t < cnt) {
        int n = n0 + t;
        g = seg[n];
        float4 s = scores4[n];
        float4 m = mArr[g];
        float4 is = isArr[g];
        w = 0.25f * (expf(s.x - m.x) * is.x + expf(s.y - m.y) * is.y +
                     expf(s.z - m.z) * is.z + expf(s.w - m.w) * is.w);
    }
    gl[t] = g;
    wl[t] = w;
    __syncthreads();
    bool bnd = (t > 0) && (t < cnt) && (gl[t] != gl[t - 1]);
    unsigned long long bm = __ballot(bnd);
    if ((t & 63) == 0) bmask[t >> 6] = bm;
    __syncthreads();

    int rs = 0;
    while (rs < cnt) {                       // wave-uniform run iteration
        int re = cnt;
        {
            int wd = (rs + 1) >> 6, bb = (rs + 1) & 63;
            for (; wd < 4; ++wd, bb = 0) {
                unsigned long long mm = bmask[wd];
                if (bb) mm &= (~0ULL) << bb;
                if (mm) { re = wd * 64 + (__ffsll(mm) - 1); break; }
            }
            if (re > cnt) re = cnt;
        }
        float acc = 0.f;
        int i = rs;
        for (; i + 8 <= re; i += 8) {
            float xv[8];
#pragma unroll
            for (int j = 0; j < 8; ++j)
                xv[j] = x[(size_t)(n0 + i + j) * 256 + t];
#pragma unroll
            for (int j = 0; j < 8; ++j) acc += wl[i + j] * xv[j];
        }
        for (; i < re; ++i) acc += wl[i] * x[(size_t)(n0 + i) * 256 + t];
        atomicAdd(&out[(size_t)gl[rs] * 256 + t], acc);
        rs = re;
    }
}

extern "C" void kernel_launch(void* const* d_in, const int* in_sizes, int n_in,
                              void* d_out, int out_size, void* d_ws, size_t ws_size,
                              hipStream_t stream) {
    const float* x  = (const float*)d_in[0];
    const int* seg  = (const int*)d_in[1];
    // d_in[2] = num_graphs scalar (G=1024, fixed by problem)
    const float* W1 = (const float*)d_in[3];
    const float* b1 = (const float*)d_in[4];
    const float* W2 = (const float*)d_in[5];
    const float* b2 = (const float*)d_in[6];
    float* out = (float*)d_out;

    const int N = in_sizes[0] / 256;     // 200000
    const int G = 1024;

    char* ws = (char*)d_ws;
    float* scores = (float*)ws;                                  // N*4 fp32 = 3.2 MB
    u16* W1T      = (u16*)(ws + (size_t)N * 16);                 // 131072 u16 = 256 KB
    float* mArr   = (float*)(ws + (size_t)N * 16 + 262144);      // G*4 fp32
    float* isArr  = mArr + (size_t)G * 4;                        // G*4 fp32

    hipMemsetAsync(d_out, 0, (size_t)G * 256 * sizeof(float), stream);
    transpose_w1<<<512, 256, 0, stream>>>(W1, W1T);
    dim3 sgrid((N + 127) / 128, 4);
    score_kernel<<<sgrid, 256, 0, stream>>>(x, W1T, b1, W2, b2, scores, N);
    segstat_kernel<<<G, 256, 0, stream>>>((const float4*)scores, seg,
                                          (float4*)mArr, (float4*)isArr, N);
    wsum_kernel<<<(N + 255) / 256, 256, 0, stream>>>(x, (const float4*)scores, seg,
                                                     (const float4*)mArr,
                                                     (const float4*)isArr, out, N);
}

// Round 5
// 383.684 us; speedup vs baseline: 1.1029x; 1.1029x over previous
//
#include <hip/hip_runtime.h>
#include <hip/hip_bf16.h>

typedef unsigned short u16;
typedef __attribute__((ext_vector_type(8))) __bf16 bf16x8;
typedef __attribute__((ext_vector_type(8))) u16 u16x8;
typedef __attribute__((ext_vector_type(4))) float f32x4;

__device__ __forceinline__ u16 f2bf(float f) {
    unsigned u = __float_as_uint(f);
    u += 0x7fffu + ((u >> 16) & 1u);   // round-to-nearest-even
    return (u16)(u >> 16);
}

__device__ __forceinline__ void gl_lds16(const void* g, void* l) {
    // direct global->LDS DMA, 16B/lane; LDS dest = wave-uniform base + lane*16
    __builtin_amdgcn_global_load_lds(
        (const __attribute__((address_space(1))) void*)g,
        (__attribute__((address_space(3))) void*)l, 16, 0, 0);
}

// ---------- kernel 0: W1 [4][256][128] fp32 -> W1T [4][128][256] bf16 ----------
// LDS-tiled transpose: coalesced reads AND writes. grid = 4 heads x 4 d-tiles.
__global__ __launch_bounds__(256) void transpose_w1(const float* __restrict__ W1,
                                                    u16* __restrict__ W1T) {
    __shared__ u16 tile[64][132];   // 64 d x 128 k, pad to 132
    const int t = threadIdx.x;
    const int h = blockIdx.x >> 2;
    const int dt = blockIdx.x & 3;
#pragma unroll
    for (int j = 0; j < 8; ++j) {
        int idx = j * 256 + t;          // 2048 float4 slots
        int r = idx >> 5;               // d-row 0..63
        int kq = idx & 31;              // float4 col
        float4 v = *reinterpret_cast<const float4*>(
            W1 + ((size_t)h * 256 + dt * 64 + r) * 128 + kq * 4);
        ushort4 o;
        o.x = f2bf(v.x); o.y = f2bf(v.y); o.z = f2bf(v.z); o.w = f2bf(v.w);
        *reinterpret_cast<ushort4*>(&tile[r][kq * 4]) = o;
    }
    __syncthreads();
#pragma unroll
    for (int j = 0; j < 4; ++j) {
        int idx = j * 256 + t;          // 1024 u16x8 slots
        int k = idx >> 3;               // 0..127
        int c8 = idx & 7;
        u16x8 o;
#pragma unroll
        for (int e = 0; e < 8; ++e) o[e] = tile[c8 * 8 + e][k];
        *reinterpret_cast<u16x8*>(W1T + ((size_t)h * 128 + k) * 256 + dt * 64 + c8 * 8) = o;
    }
}

// ---------- kernel 1: scores[N][4] = relu(x*W1+b1)*W2 + b2 ----------
// 64-node tile, 256 thr = 4 waves; wave w = head w, tile 128r x 64n (8x4 frags).
// xb: x tile as bf16 in MFMA-B-frag order (converted once at staging).
// sA: W1T rows (512 r x 32 k) staged per k-step via global_load_lds in A-frag order.
// All ds_read_b128 are lane-contiguous (conflict-free).
__global__ __launch_bounds__(256, 2) void score_kernel(
        const float* __restrict__ x, const u16* __restrict__ W1T,
        const float* __restrict__ b1, const float* __restrict__ W2,
        const float* __restrict__ b2, float* __restrict__ scores, int N) {
    __shared__ u16 xb[16384];   // [ks 0..7][nf 0..3][slot 0..63][8 bf16] = 32 KB
    __shared__ u16 sA[16384];   // [fr 0..31][slot 0..63][8 bf16]          = 32 KB

    const int t = threadIdx.x;
    const int wave = t >> 6;
    const int lane = t & 63;
    const int l15 = lane & 15;
    const int quad = lane >> 4;
    const int n0 = blockIdx.x * 64;

    // ---- stage x tile -> xb (bf16, frag order). thread: n = wave*16 + (lane>>2),
    //      k = i*32 + (lane&3)*8, slot addr = (i*256 + t)*16B. Coalesced loads.
    {
        const int nrow = wave * 16 + (lane >> 2);
        const int koff = (lane & 3) * 8;
        int nn = n0 + nrow; if (nn >= N) nn = N - 1;     // clamp (never hits: N%64==0)
        const float* src = x + (size_t)nn * 256 + koff;
        float4 v[16];
#pragma unroll
        for (int i = 0; i < 8; ++i) {
            v[2 * i]     = *reinterpret_cast<const float4*>(src + i * 32);
            v[2 * i + 1] = *reinterpret_cast<const float4*>(src + i * 32 + 4);
        }
#pragma unroll
        for (int i = 0; i < 8; ++i) {
            u16x8 o;
            o[0] = f2bf(v[2*i].x);   o[1] = f2bf(v[2*i].y);
            o[2] = f2bf(v[2*i].z);   o[3] = f2bf(v[2*i].w);
            o[4] = f2bf(v[2*i+1].x); o[5] = f2bf(v[2*i+1].y);
            o[6] = f2bf(v[2*i+1].z); o[7] = f2bf(v[2*i+1].w);
            *reinterpret_cast<u16x8*>(&xb[(i * 256 + t) * 8]) = o;
        }
    }

    // ---- sA staging: k-step ks, each wave stages fr = wave*8 .. +7 (1KB each)
    const int arr = (lane >> 2);        // row within fr-block
    const int akc = (lane & 3) * 8;     // k-chunk
    auto stageA = [&](int ks) {
        const int k0 = ks * 32;
#pragma unroll
        for (int j = 0; j < 8; ++j) {
            int fr = wave * 8 + j;
            const u16* g = W1T + (size_t)(fr * 16 + arr) * 256 + k0 + akc;
            gl_lds16(g, &sA[(size_t)fr * 512]);
        }
    };

    f32x4 acc[8][4] = {};
    stageA(0);
    __syncthreads();

    for (int ks = 0; ks < 8; ++ks) {
        bf16x8 a[8], b[4];
#pragma unroll
        for (int fr = 0; fr < 8; ++fr)
            a[fr] = *reinterpret_cast<const bf16x8*>(
                &sA[((wave * 8 + fr) * 64 + l15 * 4 + quad) * 8]);
#pragma unroll
        for (int nf = 0; nf < 4; ++nf)
            b[nf] = *reinterpret_cast<const bf16x8*>(
                &xb[((ks * 4 + nf) * 64 + l15 * 4 + quad) * 8]);
        __syncthreads();                    // all waves done reading sA[ks]
        if (ks < 7) stageA(ks + 1);         // async overwrite while MFMA runs
#pragma unroll
        for (int fr = 0; fr < 8; ++fr)
#pragma unroll
            for (int nf = 0; nf < 4; ++nf)
                acc[fr][nf] = __builtin_amdgcn_mfma_f32_16x16x32_bf16(
                    a[fr], b[nf], acc[fr][nf], 0, 0, 0);
        __syncthreads();                    // vmcnt(0) drain: staging complete
    }

    // ---- epilogue: score = sum_r relu(acc + b1)*W2, in-wave only ----
    const int h = wave;
    float4 b1v[8], w2v[8];
#pragma unroll
    for (int fr = 0; fr < 8; ++fr) {
        int rb = h * 128 + fr * 16 + quad * 4;
        b1v[fr] = *reinterpret_cast<const float4*>(b1 + rb);
        w2v[fr] = *reinterpret_cast<const float4*>(W2 + rb);
    }
    const float b2v = b2[h];
#pragma unroll
    for (int nf = 0; nf < 4; ++nf) {
        float p = 0.f;
#pragma unroll
        for (int fr = 0; fr < 8; ++fr) {
            f32x4 c = acc[fr][nf];
            p += fmaxf(c[0] + b1v[fr].x, 0.f) * w2v[fr].x
               + fmaxf(c[1] + b1v[fr].y, 0.f) * w2v[fr].y
               + fmaxf(c[2] + b1v[fr].z, 0.f) * w2v[fr].z
               + fmaxf(c[3] + b1v[fr].w, 0.f) * w2v[fr].w;
        }
        p += __shfl_xor(p, 16, 64);
        p += __shfl_xor(p, 32, 64);
        int n = n0 + nf * 16 + lane;
        if (lane < 16 && n < N)
            scores[(size_t)n * 4 + h] = p + b2v;
    }
}

// ---------- kernel 2: per-(graph,head) max and 1/sum(exp) ----------
__device__ __forceinline__ int lower_bound(const int* __restrict__ a, int n, int v) {
    int lo = 0, hi = n;
    while (lo < hi) {
        int mid = (lo + hi) >> 1;
        if (a[mid] < v) lo = mid + 1; else hi = mid;
    }
    return lo;
}

__global__ __launch_bounds__(256) void segstat_kernel(
        const float4* __restrict__ scores4, const int* __restrict__ seg,
        float4* __restrict__ mOut, float4* __restrict__ isOut, int N) {
    __shared__ float4 redm[4];
    __shared__ float4 reds[4];
    const int g = blockIdx.x;
    const int t = threadIdx.x;
    const int start = lower_bound(seg, N, g);
    const int end = lower_bound(seg, N, g + 1);

    float4 mx = make_float4(-3.4e38f, -3.4e38f, -3.4e38f, -3.4e38f);
    for (int i = start + t; i < end; i += 256) {
        float4 s = scores4[i];
        mx.x = fmaxf(mx.x, s.x); mx.y = fmaxf(mx.y, s.y);
        mx.z = fmaxf(mx.z, s.z); mx.w = fmaxf(mx.w, s.w);
    }
#pragma unroll
    for (int off = 1; off < 64; off <<= 1) {
        mx.x = fmaxf(mx.x, __shfl_xor(mx.x, off, 64));
        mx.y = fmaxf(mx.y, __shfl_xor(mx.y, off, 64));
        mx.z = fmaxf(mx.z, __shfl_xor(mx.z, off, 64));
        mx.w = fmaxf(mx.w, __shfl_xor(mx.w, off, 64));
    }
    if ((t & 63) == 0) redm[t >> 6] = mx;
    __syncthreads();
    mx = redm[0];
#pragma unroll
    for (int w = 1; w < 4; ++w) {
        mx.x = fmaxf(mx.x, redm[w].x); mx.y = fmaxf(mx.y, redm[w].y);
        mx.z = fmaxf(mx.z, redm[w].z); mx.w = fmaxf(mx.w, redm[w].w);
    }

    float4 sm = make_float4(0.f, 0.f, 0.f, 0.f);
    for (int i = start + t; i < end; i += 256) {
        float4 s = scores4[i];
        sm.x += expf(s.x - mx.x); sm.y += expf(s.y - mx.y);
        sm.z += expf(s.z - mx.z); sm.w += expf(s.w - mx.w);
    }
#pragma unroll
    for (int off = 1; off < 64; off <<= 1) {
        sm.x += __shfl_xor(sm.x, off, 64);
        sm.y += __shfl_xor(sm.y, off, 64);
        sm.z += __shfl_xor(sm.z, off, 64);
        sm.w += __shfl_xor(sm.w, off, 64);
    }
    if ((t & 63) == 0) reds[t >> 6] = sm;
    __syncthreads();
    if (t == 0) {
        float4 tot = reds[0];
        for (int w = 1; w < 4; ++w) {
            tot.x += reds[w].x; tot.y += reds[w].y;
            tot.z += reds[w].z; tot.w += reds[w].w;
        }
        bool nonempty = end > start;
        float4 m_out = nonempty ? mx : make_float4(0.f, 0.f, 0.f, 0.f);
        float4 is;
        is.x = (nonempty && tot.x > 0.f) ? 1.f / tot.x : 0.f;
        is.y = (nonempty && tot.y > 0.f) ? 1.f / tot.y : 0.f;
        is.z = (nonempty && tot.z > 0.f) ? 1.f / tot.z : 0.f;
        is.w = (nonempty && tot.w > 0.f) ? 1.f / tot.w : 0.f;
        mOut[g] = m_out;
        isOut[g] = is;
    }
}

// ---------- kernel 3: out[g][d] += avg_attn[n]*x[n][d]; 64-node strips ----------
__global__ __launch_bounds__(256) void wsum_kernel(
        const float* __restrict__ x, const float4* __restrict__ scores4,
        const int* __restrict__ seg, const float4* __restrict__ mArr,
        const float4* __restrict__ isArr, float* __restrict__ out, int N) {
    __shared__ float wl[64];
    __shared__ int gl[64];
    __shared__ unsigned long long bmask_s;
    const int t = threadIdx.x;
    const int n0 = blockIdx.x * 64;
    const int cnt = min(64, N - n0);

    if (t < 64) {                         // wave 0 exactly
        int g = -1;
        float w = 0.f;
        bool bnd = false;
        if (t < cnt) {
            int n = n0 + t;
            g = seg[n];
            float4 s = scores4[n];
            float4 m = mArr[g];
            float4 is = isArr[g];
            w = 0.25f * (expf(s.x - m.x) * is.x + expf(s.y - m.y) * is.y +
                         expf(s.z - m.z) * is.z + expf(s.w - m.w) * is.w);
            bnd = (t > 0) && (g != seg[n - 1]);
        }
        wl[t] = w;
        gl[t] = g;
        unsigned long long bm = __ballot(bnd);
        if (t == 0) bmask_s = bm;
    }
    __syncthreads();
    const unsigned long long bmask = bmask_s;

    int rs = 0;
    while (rs < cnt) {                    // wave-uniform run loop
        unsigned long long mm = (rs < 63) ? (bmask & ((~0ULL) << (rs + 1))) : 0ULL;
        int re = mm ? (__ffsll((long long)mm) - 1) : cnt;
        if (re > cnt) re = cnt;
        float acc = 0.f;
        int i = rs;
        for (; i + 8 <= re; i += 8) {
            float xv[8];
#pragma unroll
            for (int j = 0; j < 8; ++j)
                xv[j] = x[(size_t)(n0 + i + j) * 256 + t];
#pragma unroll
            for (int j = 0; j < 8; ++j) acc += wl[i + j] * xv[j];
        }
        for (; i < re; ++i) acc += wl[i] * x[(size_t)(n0 + i) * 256 + t];
        atomicAdd(&out[(size_t)gl[rs] * 256 + t], acc);
        rs = re;
    }
}

extern "C" void kernel_launch(void* const* d_in, const int* in_sizes, int n_in,
                              void* d_out, int out_size, void* d_ws, size_t ws_size,
                              hipStream_t stream) {
    const float* x  = (const float*)d_in[0];
    const int* seg  = (const int*)d_in[1];
    // d_in[2] = num_graphs scalar (G=1024, fixed by problem)
    const float* W1 = (const float*)d_in[3];
    const float* b1 = (const float*)d_in[4];
    const float* W2 = (const float*)d_in[5];
    const float* b2 = (const float*)d_in[6];
    float* out = (float*)d_out;

    const int N = in_sizes[0] / 256;     // 200000
    const int G = 1024;

    char* ws = (char*)d_ws;
    float* scores = (float*)ws;                                  // N*4 fp32 = 3.2 MB
    u16* W1T      = (u16*)(ws + (size_t)N * 16);                 // 131072 u16 = 256 KB
    float* mArr   = (float*)(ws + (size_t)N * 16 + 262144);      // G*4 fp32
    float* isArr  = mArr + (size_t)G * 4;                        // G*4 fp32

    hipMemsetAsync(d_out, 0, (size_t)G * 256 * sizeof(float), stream);
    transpose_w1<<<16, 256, 0, stream>>>(W1, W1T);
    score_kernel<<<(N + 63) / 64, 256, 0, stream>>>(x, W1T, b1, W2, b2, scores, N);
    segstat_kernel<<<G, 256, 0, stream>>>((const float4*)scores, seg,
                                          (float4*)mArr, (float4*)isArr, N);
    wsum_kernel<<<(N + 63) / 64, 256, 0, stream>>>(x, (const float4*)scores, seg,
                                                   (const float4*)mArr,
                                                   (const float4*)isArr, out, N);
}